// Round 4
// baseline (1556.295 us; speedup 1.0000x reference)
//
#include <hip/hip_runtime.h>
#include <cstdint>
#include <cstddef>

#define NN 50000
#define NE 800000
#define NREL 32
#define DIM 128
#define BN_EPS 1e-5f
#define TE 128            // edges per GEMM tile
#define CPB2 32           // chunks (blocks) per relation in k_gemm

// ---- workspace layout (units of 4 bytes) ----
#define WS_H      0
#define WS_WMOD   6400000
#define WS_SNORM  6924288
#define WS_SSRC   7724288
#define WS_SDST   8524288
#define WS_CNT    9324288
#define WS_OFF    9324320
#define WS_CURSOR 9324353
#define WS_STATS  9324385
#define WS_END    9324641

// ---------- Wmod = edge_feat[r,d] * W_R[r,d,o] ----------
__global__ void k_wmod(const float* __restrict__ ef, const float* __restrict__ WR,
                       float* __restrict__ wmod) {
    int idx = blockIdx.x * 256 + threadIdx.x;          // grid covers 32*128*128 exactly
    int r = idx >> 14;
    int d = (idx >> 7) & 127;
    wmod[idx] = ef[(r << 7) + d] * WR[idx];
}

// ---------- histogram of etype (LDS-aggregated) ----------
__global__ void k_hist(const int* __restrict__ etype, int* __restrict__ cnt) {
    __shared__ int lc[NREL];
    if (threadIdx.x < NREL) lc[threadIdx.x] = 0;
    __syncthreads();
    for (int i = blockIdx.x * blockDim.x + threadIdx.x; i < NE;
         i += gridDim.x * blockDim.x)
        atomicAdd(&lc[etype[i]], 1);
    __syncthreads();
    if (threadIdx.x < NREL) atomicAdd(&cnt[threadIdx.x], lc[threadIdx.x]);
}

// ---------- tiny exclusive scan over 32 bins ----------
__global__ void k_scan(const int* __restrict__ cnt, int* __restrict__ off,
                       int* __restrict__ cursor) {
    if (threadIdx.x == 0) {
        int a = 0;
        for (int r = 0; r < NREL; ++r) {
            off[r] = a; cursor[r] = a; a += cnt[r];
        }
        off[NREL] = a;
    }
}

// ---------- counting-sort scatter (block-reserved ranges) ----------
__global__ void k_scatter(const int* __restrict__ etype, const int* __restrict__ src,
                          const int* __restrict__ dst, const float* __restrict__ norm,
                          int* __restrict__ cursor,
                          int* __restrict__ ssrc, int* __restrict__ sdst,
                          float* __restrict__ snorm) {
    __shared__ int lc[NREL], lbase[NREL];
    int i0 = blockIdx.x * 2048;
    int i1 = min(i0 + 2048, NE);
    if (threadIdx.x < NREL) lc[threadIdx.x] = 0;
    __syncthreads();
    for (int i = i0 + threadIdx.x; i < i1; i += 256)
        atomicAdd(&lc[etype[i]], 1);
    __syncthreads();
    if (threadIdx.x < NREL) {
        lbase[threadIdx.x] = atomicAdd(&cursor[threadIdx.x], lc[threadIdx.x]);
        lc[threadIdx.x] = 0;
    }
    __syncthreads();
    for (int i = i0 + threadIdx.x; i < i1; i += 256) {
        int et = etype[i];
        int pos = lbase[et] + atomicAdd(&lc[et], 1);
        ssrc[pos] = src[i];
        sdst[pos] = dst[i];
        snorm[pos] = norm[i];
    }
}

// ---------- out2 = edge_feat @ W_rel ----------
__global__ void k_out2(const float* __restrict__ ef, const float* __restrict__ wrel,
                       float* __restrict__ out2) {
    int r = blockIdx.x;          // 32 blocks
    int o = threadIdx.x;         // 128 threads
    float y0 = 0.f, y1 = 0.f;
    #pragma unroll
    for (int d = 0; d < DIM; d += 2) {
        y0 = fmaf(ef[r * DIM + d],     wrel[d * DIM + o],       y0);
        y1 = fmaf(ef[r * DIM + d + 1], wrel[(d + 1) * DIM + o], y1);
    }
    out2[r * DIM + o] = y0 + y1;
}

// ---------- main: per-relation tiled GEMM with atomic scatter ----------
// Block = (relation r, chunk c): a contiguous slice of r's edges, processed in
// TE=128-edge tiles. Ws staged ONCE per block; Xs re-staged per tile. 512 thr.
// LDS: Xs[k][m] 64 KB + Ws[k][n] 64 KB = 128 KB -> 1 block/CU, 2 waves/SIMD.
// Thread (mi = t>>4, ni = t&15): rows mi*4..+3, cols {ni*4..+3, 64+ni*4..+3}.
// Bank math: Xs read = 4 distinct addrs x 16-way broadcast (free);
// Ws reads = 16 distinct 16B addrs covering all 32 banks 2-way (free, m136).
__global__ __launch_bounds__(512, 2)
void k_gemm(const float* __restrict__ node_feat, const float* __restrict__ wmod,
            const int* __restrict__ ssrc, const int* __restrict__ sdst,
            const float* __restrict__ snorm, const int* __restrict__ off,
            float* __restrict__ h) {
    __shared__ float Xs[DIM][TE];   // [k][m]
    __shared__ float Ws[DIM][DIM];  // [k][n]
    const int t = threadIdx.x;
    const int r = blockIdx.x / CPB2;
    const int c = blockIdx.x % CPB2;

    const int beg_r = off[r], end_r = off[r + 1];
    const int cnt_r = end_r - beg_r;
    const int L = (cnt_r + CPB2 - 1) / CPB2;
    const int s0 = beg_r + c * L;
    const int s1 = min(s0 + L, end_r);
    if (s0 >= s1) return;           // block-uniform: safe before barriers

    // ---- stage Ws once (linear copy, coalesced, conflict-free b128) ----
    {
        const float* wsrc = wmod + ((size_t)r << 14);
        float* wdst = &Ws[0][0];
        #pragma unroll
        for (int i = 0; i < 8; ++i) {
            int idx = i * 2048 + t * 4;
            *(float4*)&wdst[idx] = *(const float4*)&wsrc[idx];
        }
    }

    const int mi = t >> 4;
    const int ni = t & 15;
    const int m = t & 127;          // edge row for staging
    const int q = t >> 7;           // d-quarter for staging

    for (int tb = s0; tb < s1; tb += TE) {
        const int cnt_tile = min(TE, s1 - tb);

        __syncthreads();            // Xs free of prior readers (also fences Ws)
        // ---- stage Xs: gather node_feat[src], scale by norm, transpose ----
        {
            int   se = 0;
            float nm = 0.f;
            if (m < cnt_tile) { se = ssrc[tb + m]; nm = snorm[tb + m]; }
            const float* xp = node_feat + ((size_t)se << 7);
            #pragma unroll
            for (int i = 0; i < 8; ++i) {
                int d = q * 32 + i * 4;
                float4 v = *(const float4*)&xp[d];
                Xs[d][m]     = v.x * nm;
                Xs[d + 1][m] = v.y * nm;
                Xs[d + 2][m] = v.z * nm;
                Xs[d + 3][m] = v.w * nm;
            }
        }
        __syncthreads();

        // ---- compute: 4 rows x 8 cols per thread, 32 FMA per k-step ----
        float acc4[4][8];
        #pragma unroll
        for (int a = 0; a < 4; ++a)
            #pragma unroll
            for (int cc = 0; cc < 8; ++cc) acc4[a][cc] = 0.f;

        #pragma unroll 8
        for (int k = 0; k < DIM; ++k) {
            float4 xf = *(const float4*)&Xs[k][mi * 4];
            float4 wa = *(const float4*)&Ws[k][ni * 4];
            float4 wb = *(const float4*)&Ws[k][64 + ni * 4];
            const float xv[4] = {xf.x, xf.y, xf.z, xf.w};
            const float wv[8] = {wa.x, wa.y, wa.z, wa.w, wb.x, wb.y, wb.z, wb.w};
            #pragma unroll
            for (int a = 0; a < 4; ++a)
                #pragma unroll
                for (int cc = 0; cc < 8; ++cc)
                    acc4[a][cc] = fmaf(xv[a], wv[cc], acc4[a][cc]);
        }

        // ---- epilogue: atomic scatter rows to h[dst] ----
        #pragma unroll
        for (int a = 0; a < 4; ++a) {
            int el = mi * 4 + a;
            if (el < cnt_tile) {
                int d2 = sdst[tb + el];
                float* hp = h + ((size_t)d2 << 7);
                #pragma unroll
                for (int cc = 0; cc < 4; ++cc)
                    atomicAdd(&hp[ni * 4 + cc], acc4[a][cc]);
                #pragma unroll
                for (int cc = 0; cc < 4; ++cc)
                    atomicAdd(&hp[64 + ni * 4 + cc], acc4[a][cc + 4]);
            }
        }
    }
}

// ---------- BatchNorm stats: per-channel sum / sumsq ----------
__global__ void k_bnstat(const float* __restrict__ h, float* __restrict__ stats) {
    const int t = threadIdx.x;
    const int o = t & 127;
    const int half = t >> 7;
    float s = 0.f, ss = 0.f;
    for (int n = blockIdx.x * 2 + half; n < NN; n += gridDim.x * 2) {
        float v = h[(size_t)n * DIM + o];
        s += v; ss += v * v;
    }
    __shared__ float bs[256], bss[256];
    bs[t] = s; bss[t] = ss;
    __syncthreads();
    if (t < 128) {
        atomicAdd(&stats[o],       bs[t] + bs[t + 128]);
        atomicAdd(&stats[128 + o], bss[t] + bss[t + 128]);
    }
}

// ---------- BatchNorm apply + tanh ----------
__global__ void k_bnapply(const float* __restrict__ h, const float* __restrict__ stats,
                          const float* __restrict__ gamma, const float* __restrict__ beta,
                          float* __restrict__ out) {
    const float invN = 1.f / (float)NN;
    for (int idx = blockIdx.x * 256 + threadIdx.x; idx < NN * DIM;
         idx += gridDim.x * 256) {
        int o = idx & 127;
        float mean = stats[o] * invN;
        float var  = stats[128 + o] * invN - mean * mean;
        float v = (h[idx] - mean) * rsqrtf(var + BN_EPS) * gamma[o] + beta[o];
        out[idx] = tanhf(v);
    }
}

extern "C" void kernel_launch(void* const* d_in, const int* in_sizes, int n_in,
                              void* d_out, int out_size, void* d_ws, size_t ws_size,
                              hipStream_t stream) {
    const float* node_feat = (const float*)d_in[0];
    const float* edge_feat = (const float*)d_in[1];
    const float* W_R       = (const float*)d_in[2];
    const float* W_rel     = (const float*)d_in[3];
    const float* bn_gamma  = (const float*)d_in[4];
    const float* bn_beta   = (const float*)d_in[5];
    const float* enorm     = (const float*)d_in[6];
    const int*   src       = (const int*)d_in[7];
    const int*   dst       = (const int*)d_in[8];
    const int*   etype     = (const int*)d_in[9];

    float* ws_f = (float*)d_ws;
    int*   ws_i = (int*)d_ws;

    float* h      = ws_f + WS_H;
    float* wmod   = ws_f + WS_WMOD;
    float* snorm  = ws_f + WS_SNORM;
    int*   ssrc   = ws_i + WS_SSRC;
    int*   sdst   = ws_i + WS_SDST;
    int*   cnt    = ws_i + WS_CNT;
    int*   off    = ws_i + WS_OFF;
    int*   cursor = ws_i + WS_CURSOR;
    float* stats  = ws_f + WS_STATS;

    float* out_h  = (float*)d_out;              // N*128
    float* out2   = (float*)d_out + NN * DIM;   // 32*128

    hipMemsetAsync(h, 0, (size_t)NN * DIM * sizeof(float), stream);
    hipMemsetAsync(ws_i + WS_CNT, 0, (WS_END - WS_CNT) * sizeof(int), stream);

    k_wmod    <<<2048, 256, 0, stream>>>(edge_feat, W_R, wmod);
    k_hist    <<<256, 256, 0, stream>>>(etype, cnt);
    k_scan    <<<1, 64, 0, stream>>>(cnt, off, cursor);
    k_scatter <<<(NE + 2047) / 2048, 256, 0, stream>>>(etype, src, dst, enorm,
                                                       cursor, ssrc, sdst, snorm);
    k_out2    <<<NREL, DIM, 0, stream>>>(edge_feat, W_rel, out2);
    k_gemm    <<<NREL * CPB2, 512, 0, stream>>>(node_feat, wmod, ssrc, sdst,
                                                snorm, off, h);
    k_bnstat  <<<512, 256, 0, stream>>>(h, stats);
    k_bnapply <<<2048, 256, 0, stream>>>(h, stats, bn_gamma, bn_beta, out_h);
}

// Round 5
// 807.285 us; speedup vs baseline: 1.9278x; 1.9278x over previous
//
#include <hip/hip_runtime.h>
#include <cstdint>
#include <cstddef>

#define NN 50000
#define NE 800000
#define NREL 32
#define DIM 128
#define BN_EPS 1e-5f
#define TE 128            // edges per GEMM tile
#define CPB2 32           // chunks (blocks) per relation in k_gemm

// ---- workspace layout (units of 4 bytes) ----
#define WS_H      0
#define WS_WMOD   6400000
#define WS_SNORM  6924288
#define WS_SSRC   7724288
#define WS_SDST   8524288
#define WS_CNT    9324288
#define WS_OFF    9324320
#define WS_CURSOR 9324353
#define WS_STATS  9324385
#define WS_END    9324641

// ---------- Wmod = edge_feat[r,d] * W_R[r,d,o] ----------
__global__ void k_wmod(const float* __restrict__ ef, const float* __restrict__ WR,
                       float* __restrict__ wmod) {
    int idx = blockIdx.x * 256 + threadIdx.x;          // grid covers 32*128*128 exactly
    int r = idx >> 14;
    int d = (idx >> 7) & 127;
    wmod[idx] = ef[(r << 7) + d] * WR[idx];
}

// ---------- histogram of etype (LDS-aggregated) ----------
__global__ void k_hist(const int* __restrict__ etype, int* __restrict__ cnt) {
    __shared__ int lc[NREL];
    if (threadIdx.x < NREL) lc[threadIdx.x] = 0;
    __syncthreads();
    for (int i = blockIdx.x * blockDim.x + threadIdx.x; i < NE;
         i += gridDim.x * blockDim.x)
        atomicAdd(&lc[etype[i]], 1);
    __syncthreads();
    if (threadIdx.x < NREL) atomicAdd(&cnt[threadIdx.x], lc[threadIdx.x]);
}

// ---------- tiny exclusive scan over 32 bins ----------
__global__ void k_scan(const int* __restrict__ cnt, int* __restrict__ off,
                       int* __restrict__ cursor) {
    if (threadIdx.x == 0) {
        int a = 0;
        for (int r = 0; r < NREL; ++r) {
            off[r] = a; cursor[r] = a; a += cnt[r];
        }
        off[NREL] = a;
    }
}

// ---------- counting-sort scatter (block-reserved ranges) ----------
__global__ void k_scatter(const int* __restrict__ etype, const int* __restrict__ src,
                          const int* __restrict__ dst, const float* __restrict__ norm,
                          int* __restrict__ cursor,
                          int* __restrict__ ssrc, int* __restrict__ sdst,
                          float* __restrict__ snorm) {
    __shared__ int lc[NREL], lbase[NREL];
    int i0 = blockIdx.x * 2048;
    int i1 = min(i0 + 2048, NE);
    if (threadIdx.x < NREL) lc[threadIdx.x] = 0;
    __syncthreads();
    for (int i = i0 + threadIdx.x; i < i1; i += 256)
        atomicAdd(&lc[etype[i]], 1);
    __syncthreads();
    if (threadIdx.x < NREL) {
        lbase[threadIdx.x] = atomicAdd(&cursor[threadIdx.x], lc[threadIdx.x]);
        lc[threadIdx.x] = 0;
    }
    __syncthreads();
    for (int i = i0 + threadIdx.x; i < i1; i += 256) {
        int et = etype[i];
        int pos = lbase[et] + atomicAdd(&lc[et], 1);
        ssrc[pos] = src[i];
        sdst[pos] = dst[i];
        snorm[pos] = norm[i];
    }
}

// ---------- out2 = edge_feat @ W_rel ----------
__global__ void k_out2(const float* __restrict__ ef, const float* __restrict__ wrel,
                       float* __restrict__ out2) {
    int r = blockIdx.x;          // 32 blocks
    int o = threadIdx.x;         // 128 threads
    float y0 = 0.f, y1 = 0.f;
    #pragma unroll
    for (int d = 0; d < DIM; d += 2) {
        y0 = fmaf(ef[r * DIM + d],     wrel[d * DIM + o],       y0);
        y1 = fmaf(ef[r * DIM + d + 1], wrel[(d + 1) * DIM + o], y1);
    }
    out2[r * DIM + o] = y0 + y1;
}

// ---------- main: per-relation tiled GEMM, LDS-transposed coalesced scatter ----
// Block = (relation r, chunk c). Ws staged ONCE per block; Xs re-staged per
// TE=128-edge tile. 512 thr. LDS: Xs 64 KB + Ws 64 KB = 128 KB, 1 block/CU.
// Compute: thread (mi,ni) -> rows mi*4..+3, cols {ni*4..+3, 64+ni*4..+3}.
// Epilogue: acc -> O[m][n] in LDS (reuse Xs; b128 writes, same bank profile as
// contiguous b128 = baseline cost), then wave w scatters rows 16w..16w+15 with
// 64-lane-CONTIGUOUS atomics (r2's strided atomics caused 4x write traffic).
__global__ __launch_bounds__(512, 2)
void k_gemm(const float* __restrict__ node_feat, const float* __restrict__ wmod,
            const int* __restrict__ ssrc, const int* __restrict__ sdst,
            const float* __restrict__ snorm, const int* __restrict__ off,
            float* __restrict__ h) {
    __shared__ float Xs[DIM][TE];   // [k][m] during compute; O[m][n] in epilogue
    __shared__ float Ws[DIM][DIM];  // [k][n]
    const int t = threadIdx.x;
    const int r = blockIdx.x / CPB2;
    const int c = blockIdx.x % CPB2;

    const int beg_r = off[r], end_r = off[r + 1];
    const int cnt_r = end_r - beg_r;
    const int L = (cnt_r + CPB2 - 1) / CPB2;
    const int s0 = beg_r + c * L;
    const int s1 = min(s0 + L, end_r);
    if (s0 >= s1) return;           // block-uniform: safe before barriers

    // ---- stage Ws once (linear copy, coalesced, conflict-free b128) ----
    {
        const float* wsrc = wmod + ((size_t)r << 14);
        float* wdst = &Ws[0][0];
        #pragma unroll
        for (int i = 0; i < 8; ++i) {
            int idx = i * 2048 + t * 4;
            *(float4*)&wdst[idx] = *(const float4*)&wsrc[idx];
        }
    }

    const int mi = t >> 4;
    const int ni = t & 15;
    const int m = t & 127;          // edge row for staging
    const int q = t >> 7;           // d-quarter for staging
    const int wv = t >> 6;          // wave id 0..7 (epilogue rows 16wv..+15)
    const int l  = t & 63;          // lane (epilogue column)

    for (int tb = s0; tb < s1; tb += TE) {
        const int cnt_tile = min(TE, s1 - tb);

        __syncthreads();            // prev epilogue's O-reads done; Ws visible
        // ---- stage Xs: gather node_feat[src], scale by norm, transpose ----
        {
            int   se = 0;
            float nm = 0.f;
            if (m < cnt_tile) { se = ssrc[tb + m]; nm = snorm[tb + m]; }
            const float* xp = node_feat + ((size_t)se << 7);
            #pragma unroll
            for (int i = 0; i < 8; ++i) {
                int d = q * 32 + i * 4;
                float4 v = *(const float4*)&xp[d];
                Xs[d][m]     = v.x * nm;
                Xs[d + 1][m] = v.y * nm;
                Xs[d + 2][m] = v.z * nm;
                Xs[d + 3][m] = v.w * nm;
            }
        }
        __syncthreads();

        // ---- compute: 4 rows x 8 cols per thread, 32 FMA per k-step ----
        float acc4[4][8];
        #pragma unroll
        for (int a = 0; a < 4; ++a)
            #pragma unroll
            for (int cc = 0; cc < 8; ++cc) acc4[a][cc] = 0.f;

        #pragma unroll 8
        for (int k = 0; k < DIM; ++k) {
            float4 xf = *(const float4*)&Xs[k][mi * 4];
            float4 wa = *(const float4*)&Ws[k][ni * 4];
            float4 wb = *(const float4*)&Ws[k][64 + ni * 4];
            const float xv[4] = {xf.x, xf.y, xf.z, xf.w};
            const float wv8[8] = {wa.x, wa.y, wa.z, wa.w, wb.x, wb.y, wb.z, wb.w};
            #pragma unroll
            for (int a = 0; a < 4; ++a)
                #pragma unroll
                for (int cc = 0; cc < 8; ++cc)
                    acc4[a][cc] = fmaf(xv[a], wv8[cc], acc4[a][cc]);
        }

        __syncthreads();            // compute's Xs reads done before O overwrite
        // ---- transpose acc into O[m][n] (reuse Xs) ----
        {
            float* O = &Xs[0][0];
            #pragma unroll
            for (int a = 0; a < 4; ++a) {
                int row = mi * 4 + a;
                *(float4*)&O[row * DIM + ni * 4] =
                    make_float4(acc4[a][0], acc4[a][1], acc4[a][2], acc4[a][3]);
                *(float4*)&O[row * DIM + 64 + ni * 4] =
                    make_float4(acc4[a][4], acc4[a][5], acc4[a][6], acc4[a][7]);
            }
        }
        __syncthreads();
        // ---- coalesced atomic scatter: wave-contiguous 64x4B per instr ----
        {
            const float* O = &Xs[0][0];
            #pragma unroll
            for (int rr = 0; rr < 16; ++rr) {
                int row = wv * 16 + rr;             // wave-uniform
                if (row < cnt_tile) {
                    int d2 = sdst[tb + row];
                    float* hp = h + ((size_t)d2 << 7);
                    atomicAdd(&hp[l],      O[row * DIM + l]);
                    atomicAdd(&hp[64 + l], O[row * DIM + 64 + l]);
                }
            }
        }
    }
}

// ---------- BatchNorm stats: per-channel sum / sumsq ----------
__global__ void k_bnstat(const float* __restrict__ h, float* __restrict__ stats) {
    const int t = threadIdx.x;
    const int o = t & 127;
    const int half = t >> 7;
    float s = 0.f, ss = 0.f;
    for (int n = blockIdx.x * 2 + half; n < NN; n += gridDim.x * 2) {
        float v = h[(size_t)n * DIM + o];
        s += v; ss += v * v;
    }
    __shared__ float bs[256], bss[256];
    bs[t] = s; bss[t] = ss;
    __syncthreads();
    if (t < 128) {
        atomicAdd(&stats[o],       bs[t] + bs[t + 128]);
        atomicAdd(&stats[128 + o], bss[t] + bss[t + 128]);
    }
}

// ---------- BatchNorm apply + tanh ----------
__global__ void k_bnapply(const float* __restrict__ h, const float* __restrict__ stats,
                          const float* __restrict__ gamma, const float* __restrict__ beta,
                          float* __restrict__ out) {
    const float invN = 1.f / (float)NN;
    for (int idx = blockIdx.x * 256 + threadIdx.x; idx < NN * DIM;
         idx += gridDim.x * 256) {
        int o = idx & 127;
        float mean = stats[o] * invN;
        float var  = stats[128 + o] * invN - mean * mean;
        float v = (h[idx] - mean) * rsqrtf(var + BN_EPS) * gamma[o] + beta[o];
        out[idx] = tanhf(v);
    }
}

extern "C" void kernel_launch(void* const* d_in, const int* in_sizes, int n_in,
                              void* d_out, int out_size, void* d_ws, size_t ws_size,
                              hipStream_t stream) {
    const float* node_feat = (const float*)d_in[0];
    const float* edge_feat = (const float*)d_in[1];
    const float* W_R       = (const float*)d_in[2];
    const float* W_rel     = (const float*)d_in[3];
    const float* bn_gamma  = (const float*)d_in[4];
    const float* bn_beta   = (const float*)d_in[5];
    const float* enorm     = (const float*)d_in[6];
    const int*   src       = (const int*)d_in[7];
    const int*   dst       = (const int*)d_in[8];
    const int*   etype     = (const int*)d_in[9];

    float* ws_f = (float*)d_ws;
    int*   ws_i = (int*)d_ws;

    float* h      = ws_f + WS_H;
    float* wmod   = ws_f + WS_WMOD;
    float* snorm  = ws_f + WS_SNORM;
    int*   ssrc   = ws_i + WS_SSRC;
    int*   sdst   = ws_i + WS_SDST;
    int*   cnt    = ws_i + WS_CNT;
    int*   off    = ws_i + WS_OFF;
    int*   cursor = ws_i + WS_CURSOR;
    float* stats  = ws_f + WS_STATS;

    float* out_h  = (float*)d_out;              // N*128
    float* out2   = (float*)d_out + NN * DIM;   // 32*128

    hipMemsetAsync(h, 0, (size_t)NN * DIM * sizeof(float), stream);
    hipMemsetAsync(ws_i + WS_CNT, 0, (WS_END - WS_CNT) * sizeof(int), stream);

    k_wmod    <<<2048, 256, 0, stream>>>(edge_feat, W_R, wmod);
    k_hist    <<<256, 256, 0, stream>>>(etype, cnt);
    k_scan    <<<1, 64, 0, stream>>>(cnt, off, cursor);
    k_scatter <<<(NE + 2047) / 2048, 256, 0, stream>>>(etype, src, dst, enorm,
                                                       cursor, ssrc, sdst, snorm);
    k_out2    <<<NREL, DIM, 0, stream>>>(edge_feat, W_rel, out2);
    k_gemm    <<<NREL * CPB2, 512, 0, stream>>>(node_feat, wmod, ssrc, sdst,
                                                snorm, off, h);
    k_bnstat  <<<512, 256, 0, stream>>>(h, stats);
    k_bnapply <<<2048, 256, 0, stream>>>(h, stats, bn_gamma, bn_beta, out_h);
}

// Round 6
// 584.196 us; speedup vs baseline: 2.6640x; 1.3819x over previous
//
#include <hip/hip_runtime.h>
#include <cstdint>
#include <cstddef>

#define NN 50000
#define NE 800000
#define NREL 32
#define DIM 128
#define BN_EPS 1e-5f
#define WTE 16            // edges per wave-tile in k_gemm

// ---- workspace layout (units of 4 bytes) ----
#define WS_H      0
#define WS_WMOD   6400000
#define WS_SNORM  6924288
#define WS_SSRC   7724288
#define WS_SDST   8524288
#define WS_CNT    9324288
#define WS_OFF    9324320
#define WS_CURSOR 9324353
#define WS_STATS  9324385
#define WS_END    9324641

// ---------- Wmod = edge_feat[r,d] * W_R[r,d,o] ----------
__global__ void k_wmod(const float* __restrict__ ef, const float* __restrict__ WR,
                       float* __restrict__ wmod) {
    int idx = blockIdx.x * 256 + threadIdx.x;          // grid covers 32*128*128 exactly
    int r = idx >> 14;
    int d = (idx >> 7) & 127;
    wmod[idx] = ef[(r << 7) + d] * WR[idx];
}

// ---------- histogram of etype (LDS-aggregated) ----------
__global__ void k_hist(const int* __restrict__ etype, int* __restrict__ cnt) {
    __shared__ int lc[NREL];
    if (threadIdx.x < NREL) lc[threadIdx.x] = 0;
    __syncthreads();
    for (int i = blockIdx.x * blockDim.x + threadIdx.x; i < NE;
         i += gridDim.x * blockDim.x)
        atomicAdd(&lc[etype[i]], 1);
    __syncthreads();
    if (threadIdx.x < NREL) atomicAdd(&cnt[threadIdx.x], lc[threadIdx.x]);
}

// ---------- tiny exclusive scan over 32 bins ----------
__global__ void k_scan(const int* __restrict__ cnt, int* __restrict__ off,
                       int* __restrict__ cursor) {
    if (threadIdx.x == 0) {
        int a = 0;
        for (int r = 0; r < NREL; ++r) {
            off[r] = a; cursor[r] = a; a += cnt[r];
        }
        off[NREL] = a;
    }
}

// ---------- counting-sort scatter (block-reserved ranges) ----------
__global__ void k_scatter(const int* __restrict__ etype, const int* __restrict__ src,
                          const int* __restrict__ dst, const float* __restrict__ norm,
                          int* __restrict__ cursor,
                          int* __restrict__ ssrc, int* __restrict__ sdst,
                          float* __restrict__ snorm) {
    __shared__ int lc[NREL], lbase[NREL];
    int i0 = blockIdx.x * 2048;
    int i1 = min(i0 + 2048, NE);
    if (threadIdx.x < NREL) lc[threadIdx.x] = 0;
    __syncthreads();
    for (int i = i0 + threadIdx.x; i < i1; i += 256)
        atomicAdd(&lc[etype[i]], 1);
    __syncthreads();
    if (threadIdx.x < NREL) {
        lbase[threadIdx.x] = atomicAdd(&cursor[threadIdx.x], lc[threadIdx.x]);
        lc[threadIdx.x] = 0;
    }
    __syncthreads();
    for (int i = i0 + threadIdx.x; i < i1; i += 256) {
        int et = etype[i];
        int pos = lbase[et] + atomicAdd(&lc[et], 1);
        ssrc[pos] = src[i];
        sdst[pos] = dst[i];
        snorm[pos] = norm[i];
    }
}

// ---------- out2 = edge_feat @ W_rel ----------
__global__ void k_out2(const float* __restrict__ ef, const float* __restrict__ wrel,
                       float* __restrict__ out2) {
    int r = blockIdx.x;          // 32 blocks
    int o = threadIdx.x;         // 128 threads
    float y0 = 0.f, y1 = 0.f;
    #pragma unroll
    for (int d = 0; d < DIM; d += 2) {
        y0 = fmaf(ef[r * DIM + d],     wrel[d * DIM + o],       y0);
        y1 = fmaf(ef[r * DIM + d + 1], wrel[(d + 1) * DIM + o], y1);
    }
    out2[r * DIM + o] = y0 + y1;
}

// ---------- main: wave-independent pipelined GEMM, NO block barriers in loop ----
// Grid = 32 rel x 8 blocks (=256 = 1/CU). Block: Ws[128][128] (64 KB, staged
// once, one __syncthreads ever) + 8 wave-private slabs Xw[wv][128][16] (64 KB).
// Each wave loops over its own 16-edge tiles: gather->slab, compute 4x8 regs,
// transpose acc into slab as O[16][128], 64-lane-contiguous atomics. Only
// wave_barrier() (compiler fences; LDS in-order per wave, slab wave-private).
// No __syncthreads in loop => no vmcnt(0) drain => atomics fire-and-forget,
// 8 desynchronized waves hide each other's gather/atomic latency.
__global__ __launch_bounds__(512, 2)
void k_gemm(const float* __restrict__ node_feat, const float* __restrict__ wmod,
            const int* __restrict__ ssrc, const int* __restrict__ sdst,
            const float* __restrict__ snorm, const int* __restrict__ off,
            float* __restrict__ h) {
    __shared__ float Ws[DIM][DIM];       // [k][n], 64 KB
    __shared__ float Xw[8][DIM][WTE];    // wave slabs: [k][m] then O[16][128]
    const int t = threadIdx.x;
    const int r  = blockIdx.x >> 3;
    const int bq = blockIdx.x & 7;

    // ---- stage Ws once (coalesced, conflict-free b128) ----
    {
        const float* wsrc = wmod + ((size_t)r << 14);
        float* wdst = &Ws[0][0];
        #pragma unroll
        for (int i = 0; i < 8; ++i) {
            int idx = i * 2048 + t * 4;
            *(float4*)&wdst[idx] = *(const float4*)&wsrc[idx];
        }
    }
    __syncthreads();                     // the ONLY block barrier

    const int wv = t >> 6;               // wave id 0..7
    const int l  = t & 63;               // lane
    float (*Xs)[WTE] = Xw[wv];           // this wave's slab
    const int seg  = l >> 4;             // 0..3  (staging 64B segment)
    const int srow = l & 15;             // staging edge row
    const int cm = l >> 4;               // compute row group: rows cm*4..+3
    const int cn = l & 15;               // compute col group

    // wave's edge range: relation r -> 8 blocks -> 8 waves
    const int beg_r = off[r], end_r = off[r + 1];
    const int cnt_r = end_r - beg_r;
    const int Lb = (cnt_r + 7) >> 3;
    const int b0 = beg_r + bq * Lb;
    const int b1 = min(b0 + Lb, end_r);
    const int span = b1 > b0 ? b1 - b0 : 0;
    const int Lw = (span + 7) >> 3;
    const int s0 = b0 + wv * Lw;
    const int s1 = min(s0 + Lw, b1);

    for (int tb = s0; tb < s1; tb += WTE) {
        const int cnt_t = min(WTE, s1 - tb);

        // ---- gather x[src]*norm into slab [k][m] (16 line-req / inst) ----
        int   se = 0;
        float nm = 0.f;
        if (srow < cnt_t) { se = ssrc[tb + srow]; nm = snorm[tb + srow]; }
        const float* xp = node_feat + ((size_t)se << 7);
        #pragma unroll
        for (int i = 0; i < 8; ++i) {
            int d0 = i * 16 + seg * 4;   // lane covers 16B of a 64B row segment
            float4 v = *(const float4*)&xp[d0];
            Xs[d0][srow]     = v.x * nm;
            Xs[d0 + 1][srow] = v.y * nm;
            Xs[d0 + 2][srow] = v.z * nm;
            Xs[d0 + 3][srow] = v.w * nm;
        }
        __builtin_amdgcn_wave_barrier();

        // ---- compute: 4 rows x 8 cols per lane, 32 FMA per k-step ----
        float acc[4][8];
        #pragma unroll
        for (int a = 0; a < 4; ++a)
            #pragma unroll
            for (int cc = 0; cc < 8; ++cc) acc[a][cc] = 0.f;

        #pragma unroll 8
        for (int k = 0; k < DIM; ++k) {
            float4 xf = *(const float4*)&Xs[k][cm * 4];
            float4 wa = *(const float4*)&Ws[k][cn * 4];
            float4 wb = *(const float4*)&Ws[k][64 + cn * 4];
            const float xv[4] = {xf.x, xf.y, xf.z, xf.w};
            const float wv8[8] = {wa.x, wa.y, wa.z, wa.w, wb.x, wb.y, wb.z, wb.w};
            #pragma unroll
            for (int a = 0; a < 4; ++a)
                #pragma unroll
                for (int cc = 0; cc < 8; ++cc)
                    acc[a][cc] = fmaf(xv[a], wv8[cc], acc[a][cc]);
        }
        __builtin_amdgcn_wave_barrier();

        // ---- transpose acc into slab as O[16][128] (wave-private reuse) ----
        float* O = &Xs[0][0];            // 2048 floats
        #pragma unroll
        for (int a = 0; a < 4; ++a) {
            int row = cm * 4 + a;
            *(float4*)&O[row * DIM + cn * 4] =
                make_float4(acc[a][0], acc[a][1], acc[a][2], acc[a][3]);
            *(float4*)&O[row * DIM + 64 + cn * 4] =
                make_float4(acc[a][4], acc[a][5], acc[a][6], acc[a][7]);
        }
        __builtin_amdgcn_wave_barrier();

        // ---- coalesced atomic scatter: 64x4B contiguous per instr ----
        #pragma unroll
        for (int rr = 0; rr < WTE; ++rr) {
            if (rr < cnt_t) {            // wave-uniform guard
                int d2 = sdst[tb + rr];
                float* hp = h + ((size_t)d2 << 7);
                atomicAdd(&hp[l],      O[rr * DIM + l]);
                atomicAdd(&hp[64 + l], O[rr * DIM + 64 + l]);
            }
        }
        __builtin_amdgcn_wave_barrier(); // scatter LDS reads before next stage
    }
}

// ---------- BatchNorm stats: per-channel sum / sumsq ----------
__global__ void k_bnstat(const float* __restrict__ h, float* __restrict__ stats) {
    const int t = threadIdx.x;
    const int o = t & 127;
    const int half = t >> 7;
    float s = 0.f, ss = 0.f;
    for (int n = blockIdx.x * 2 + half; n < NN; n += gridDim.x * 2) {
        float v = h[(size_t)n * DIM + o];
        s += v; ss += v * v;
    }
    __shared__ float bs[256], bss[256];
    bs[t] = s; bss[t] = ss;
    __syncthreads();
    if (t < 128) {
        atomicAdd(&stats[o],       bs[t] + bs[t + 128]);
        atomicAdd(&stats[128 + o], bss[t] + bss[t + 128]);
    }
}

// ---------- BatchNorm apply + tanh ----------
__global__ void k_bnapply(const float* __restrict__ h, const float* __restrict__ stats,
                          const float* __restrict__ gamma, const float* __restrict__ beta,
                          float* __restrict__ out) {
    const float invN = 1.f / (float)NN;
    for (int idx = blockIdx.x * 256 + threadIdx.x; idx < NN * DIM;
         idx += gridDim.x * 256) {
        int o = idx & 127;
        float mean = stats[o] * invN;
        float var  = stats[128 + o] * invN - mean * mean;
        float v = (h[idx] - mean) * rsqrtf(var + BN_EPS) * gamma[o] + beta[o];
        out[idx] = tanhf(v);
    }
}

extern "C" void kernel_launch(void* const* d_in, const int* in_sizes, int n_in,
                              void* d_out, int out_size, void* d_ws, size_t ws_size,
                              hipStream_t stream) {
    const float* node_feat = (const float*)d_in[0];
    const float* edge_feat = (const float*)d_in[1];
    const float* W_R       = (const float*)d_in[2];
    const float* W_rel     = (const float*)d_in[3];
    const float* bn_gamma  = (const float*)d_in[4];
    const float* bn_beta   = (const float*)d_in[5];
    const float* enorm     = (const float*)d_in[6];
    const int*   src       = (const int*)d_in[7];
    const int*   dst       = (const int*)d_in[8];
    const int*   etype     = (const int*)d_in[9];

    float* ws_f = (float*)d_ws;
    int*   ws_i = (int*)d_ws;

    float* h      = ws_f + WS_H;
    float* wmod   = ws_f + WS_WMOD;
    float* snorm  = ws_f + WS_SNORM;
    int*   ssrc   = ws_i + WS_SSRC;
    int*   sdst   = ws_i + WS_SDST;
    int*   cnt    = ws_i + WS_CNT;
    int*   off    = ws_i + WS_OFF;
    int*   cursor = ws_i + WS_CURSOR;
    float* stats  = ws_f + WS_STATS;

    float* out_h  = (float*)d_out;              // N*128
    float* out2   = (float*)d_out + NN * DIM;   // 32*128

    hipMemsetAsync(h, 0, (size_t)NN * DIM * sizeof(float), stream);
    hipMemsetAsync(ws_i + WS_CNT, 0, (WS_END - WS_CNT) * sizeof(int), stream);

    k_wmod    <<<2048, 256, 0, stream>>>(edge_feat, W_R, wmod);
    k_hist    <<<256, 256, 0, stream>>>(etype, cnt);
    k_scan    <<<1, 64, 0, stream>>>(cnt, off, cursor);
    k_scatter <<<(NE + 2047) / 2048, 256, 0, stream>>>(etype, src, dst, enorm,
                                                       cursor, ssrc, sdst, snorm);
    k_out2    <<<NREL, DIM, 0, stream>>>(edge_feat, W_rel, out2);
    k_gemm    <<<NREL * 8, 512, 0, stream>>>(node_feat, wmod, ssrc, sdst,
                                             snorm, off, h);
    k_bnstat  <<<512, 256, 0, stream>>>(h, stats);
    k_bnapply <<<2048, 256, 0, stream>>>(h, stats, bn_gamma, bn_beta, out_h);
}

// Round 8
// 531.475 us; speedup vs baseline: 2.9283x; 1.0992x over previous
//
#include <hip/hip_runtime.h>
#include <cstdint>
#include <cstddef>

#define NN 50000
#define NE 800000
#define NREL 32
#define DIM 128
#define BN_EPS 1e-5f
#define WTE 16            // edges per wave-tile (MFMA M=16)

// ---- workspace layout (units of 4 bytes) ----
// whi/wlo: W frags as ushort, each 32*16384 ushorts = 262144 floats
#define WS_H      0
#define WS_WFRAG  6400000
#define WS_SNORM  6924288
#define WS_SSRC   7724288
#define WS_SDST   8524288
#define WS_CNT    9324288
#define WS_OFF    9324320
#define WS_CURSOR 9324353
#define WS_STATS  9324385
#define WS_END    9324641

typedef __attribute__((ext_vector_type(8))) short bf16x8;
typedef __attribute__((ext_vector_type(4))) float f32x4;
typedef __attribute__((ext_vector_type(8))) unsigned short ush8;

__device__ __forceinline__ unsigned short f2bf(float f) {      // RNE to bf16
    unsigned int u = __float_as_uint(f);
    return (unsigned short)((u + 0x7fffu + ((u >> 16) & 1u)) >> 16);
}
__device__ __forceinline__ float bf2f(unsigned short b) {
    return __uint_as_float(((unsigned int)b) << 16);
}

// ---------- fused prep: W-frag pack + hist + out2 ----------
// blocks [0,2048): pack wmod=ef*WR into split-bf16 MFMA B-fragment order.
// Frag layout per relation: [kc(4)][nc(8)][lane(64)][j(8)] where the lane
// holds B[k=kc*32+8*(lane>>4)+j][n=nc*16+(lane&15)]  (verified m90-97 pattern).
// blocks [2048,2080): out2 = edge_feat @ W_rel.  blocks [2080,2144): etype hist.
__global__ void k_prep(const float* __restrict__ ef, const float* __restrict__ WR,
                       const float* __restrict__ wrel, const int* __restrict__ etype,
                       unsigned short* __restrict__ whi, unsigned short* __restrict__ wlo,
                       float* __restrict__ out2, int* __restrict__ cnt) {
    int b = blockIdx.x;
    if (b < 2048) {
        int idx = b * 256 + threadIdx.x;           // covers 32*128*128
        int r = idx >> 14, k = (idx >> 7) & 127, n = idx & 127;
        float w = ef[(r << 7) + k] * WR[idx];
        unsigned short hi = f2bf(w);
        unsigned short lo = f2bf(w - bf2f(hi));
        int kc = k >> 5, j = k & 7;
        int lane = (((k >> 3) & 3) << 4) | (n & 15);
        int nc = n >> 4;
        int off = (r << 14) + (((((kc << 3) + nc) << 6) + lane) << 3) + j;
        whi[off] = hi;
        wlo[off] = lo;
    } else if (b < 2080) {
        int r = b - 2048;
        int o = threadIdx.x;
        if (o < DIM) {
            float y0 = 0.f, y1 = 0.f;
            #pragma unroll
            for (int d = 0; d < DIM; d += 2) {
                y0 = fmaf(ef[r * DIM + d],     wrel[d * DIM + o],       y0);
                y1 = fmaf(ef[r * DIM + d + 1], wrel[(d + 1) * DIM + o], y1);
            }
            out2[r * DIM + o] = y0 + y1;
        }
    } else {
        __shared__ int lc[NREL];
        if (threadIdx.x < NREL) lc[threadIdx.x] = 0;
        __syncthreads();
        for (int i = (b - 2080) * 256 + threadIdx.x; i < NE; i += 64 * 256)
            atomicAdd(&lc[etype[i]], 1);
        __syncthreads();
        if (threadIdx.x < NREL) atomicAdd(&cnt[threadIdx.x], lc[threadIdx.x]);
    }
}

// ---------- tiny exclusive scan over 32 bins ----------
__global__ void k_scan(const int* __restrict__ cnt, int* __restrict__ off,
                       int* __restrict__ cursor) {
    if (threadIdx.x == 0) {
        int a = 0;
        for (int r = 0; r < NREL; ++r) {
            off[r] = a; cursor[r] = a; a += cnt[r];
        }
        off[NREL] = a;
    }
}

// ---------- counting-sort scatter + h zeroing ----------
__global__ void k_scatter(const int* __restrict__ etype, const int* __restrict__ src,
                          const int* __restrict__ dst, const float* __restrict__ norm,
                          int* __restrict__ cursor,
                          int* __restrict__ ssrc, int* __restrict__ sdst,
                          float* __restrict__ snorm, float* __restrict__ hbuf) {
    // zero h (runs before k_gemm via stream order)
    float4 z4 = make_float4(0.f, 0.f, 0.f, 0.f);
    for (int i = blockIdx.x * 256 + threadIdx.x; i < NN * DIM / 4;
         i += gridDim.x * 256)
        ((float4*)hbuf)[i] = z4;

    __shared__ int lc[NREL], lbase[NREL];
    int i0 = blockIdx.x * 2048;
    int i1 = min(i0 + 2048, NE);
    if (threadIdx.x < NREL) lc[threadIdx.x] = 0;
    __syncthreads();
    for (int i = i0 + threadIdx.x; i < i1; i += 256)
        atomicAdd(&lc[etype[i]], 1);
    __syncthreads();
    if (threadIdx.x < NREL) {
        lbase[threadIdx.x] = atomicAdd(&cursor[threadIdx.x], lc[threadIdx.x]);
        lc[threadIdx.x] = 0;
    }
    __syncthreads();
    for (int i = i0 + threadIdx.x; i < i1; i += 256) {
        int et = etype[i];
        int pos = lbase[et] + atomicAdd(&lc[et], 1);
        ssrc[pos] = src[i];
        sdst[pos] = dst[i];
        snorm[pos] = norm[i];
    }
}

// ---------- main: split-bf16 MFMA GEMM, wave-independent, no block barriers ----
// Y = Xhi*Whi + Xlo*Whi + Xhi*Wlo  (lo*lo dropped, ~2^-18 rel).
// Grid = 32 rel x 8 blocks (1/CU). Block: W frags staged once in LDS (64 KB,
// one __syncthreads), per-wave O scratch 8x8 KB. Per 16-edge tile per wave:
// X frags gathered DIRECTLY global->reg in MFMA A-layout (lane: edge=l&15,
// k=(l>>4)*8+j), split hi/lo, 96 mfma_f32_16x16x32_bf16, D transposed through
// swizzled O scratch, 64-lane-contiguous atomics (r5's validated epilogue).
__global__ __launch_bounds__(512, 2)
void k_gemm(const float* __restrict__ node_feat,
            const unsigned short* __restrict__ whi,
            const unsigned short* __restrict__ wlo,
            const int* __restrict__ ssrc, const int* __restrict__ sdst,
            const float* __restrict__ snorm, const int* __restrict__ off,
            float* __restrict__ h) {
    __shared__ unsigned short WfHi[16384], WfLo[16384];   // 64 KB
    __shared__ float Os[8][WTE * DIM];                    // 64 KB wave scratch
    const int t = threadIdx.x;
    const int r  = blockIdx.x >> 3;
    const int bq = blockIdx.x & 7;

    // ---- stage W fragments once (linear copy, coalesced) ----
    {
        const unsigned short* gh = whi + (r << 14);
        const unsigned short* gl = wlo + (r << 14);
        #pragma unroll
        for (int i = 0; i < 4; ++i) {
            int idx = i * 4096 + t * 8;
            *(ush8*)&WfHi[idx] = *(const ush8*)&gh[idx];
            *(ush8*)&WfLo[idx] = *(const ush8*)&gl[idx];
        }
    }
    __syncthreads();                     // the ONLY block barrier

    const int wv = t >> 6;               // wave 0..7
    const int l  = t & 63;               // lane
    const int er = l & 15;               // edge row within tile (A row)
    const int kg = l >> 4;               // k-group (A k-chunk, D row-group)
    float* O = Os[wv];

    const int beg_r = off[r], end_r = off[r + 1];
    const int cnt_r = end_r - beg_r;
    const int Lb = (cnt_r + 7) >> 3;
    const int b0 = beg_r + bq * Lb;
    const int b1 = min(b0 + Lb, end_r);
    const int span = b1 > b0 ? b1 - b0 : 0;
    const int Lw = (span + 7) >> 3;
    const int s0 = b0 + wv * Lw;
    const int s1 = min(s0 + Lw, b1);

    for (int tb = s0; tb < s1; tb += WTE) {
        const int cnt_t = min(WTE, s1 - tb);

        int   se = 0;
        float nm = 0.f;
        if (er < cnt_t) { se = ssrc[tb + er]; nm = snorm[tb + er]; }
        const float* xp = node_feat + ((size_t)se << 7) + kg * 8;

        f32x4 acc[8];
        const f32x4 zero4 = {0.f, 0.f, 0.f, 0.f};
        #pragma unroll
        for (int nc = 0; nc < 8; ++nc) acc[nc] = zero4;

        #pragma unroll
        for (int kc = 0; kc < 4; ++kc) {
            // A fragment: 8 contiguous k floats from this lane's edge row
            float4 x0 = *(const float4*)&xp[kc * 32];
            float4 x1 = *(const float4*)&xp[kc * 32 + 4];
            float xs[8] = {x0.x * nm, x0.y * nm, x0.z * nm, x0.w * nm,
                           x1.x * nm, x1.y * nm, x1.z * nm, x1.w * nm};
            bf16x8 ah, al;
            #pragma unroll
            for (int j = 0; j < 8; ++j) {
                unsigned short hb = f2bf(xs[j]);
                ah[j] = (short)hb;
                al[j] = (short)f2bf(xs[j] - bf2f(hb));
            }
            #pragma unroll
            for (int nc = 0; nc < 8; ++nc) {
                int boff = ((((kc << 3) + nc) << 6) + l) << 3;
                bf16x8 bh = *(const bf16x8*)&WfHi[boff];
                bf16x8 bl = *(const bf16x8*)&WfLo[boff];
                acc[nc] = __builtin_amdgcn_mfma_f32_16x16x32_bf16(ah, bh, acc[nc], 0, 0, 0);
                acc[nc] = __builtin_amdgcn_mfma_f32_16x16x32_bf16(al, bh, acc[nc], 0, 0, 0);
                acc[nc] = __builtin_amdgcn_mfma_f32_16x16x32_bf16(ah, bl, acc[nc], 0, 0, 0);
            }
        }
        __builtin_amdgcn_wave_barrier();

        // ---- D -> O[row][col'] with col' = (col + 2*row) & 127 (2-way max) ----
        // D layout (m89): col = lane&15 (=er), row = (lane>>4)*4 + q (=kg*4+q)
        #pragma unroll
        for (int nc = 0; nc < 8; ++nc) {
            #pragma unroll
            for (int q = 0; q < 4; ++q) {
                int row = kg * 4 + q;
                int c = nc * 16 + er;
                O[row * DIM + ((c + 2 * row) & 127)] = acc[nc][q];
            }
        }
        __builtin_amdgcn_wave_barrier();

        // ---- coalesced atomic scatter: 64x4B contiguous per instr ----
        #pragma unroll
        for (int rr = 0; rr < WTE; ++rr) {
            if (rr < cnt_t) {            // wave-uniform guard
                int d2 = sdst[tb + rr];
                float* hp = h + ((size_t)d2 << 7);
                atomicAdd(&hp[l],      O[rr * DIM + ((l + 2 * rr) & 127)]);
                atomicAdd(&hp[64 + l], O[rr * DIM + ((64 + l + 2 * rr) & 127)]);
            }
        }
        __builtin_amdgcn_wave_barrier();
    }
}

// ---------- BatchNorm stats: per-channel sum / sumsq ----------
__global__ void k_bnstat(const float* __restrict__ h, float* __restrict__ stats) {
    const int t = threadIdx.x;
    const int o = t & 127;
    const int half = t >> 7;
    float s = 0.f, ss = 0.f;
    for (int n = blockIdx.x * 2 + half; n < NN; n += gridDim.x * 2) {
        float v = h[(size_t)n * DIM + o];
        s += v; ss += v * v;
    }
    __shared__ float bs[256], bss[256];
    bs[t] = s; bss[t] = ss;
    __syncthreads();
    if (t < 128) {
        atomicAdd(&stats[o],       bs[t] + bs[t + 128]);
        atomicAdd(&stats[128 + o], bss[t] + bss[t + 128]);
    }
}

// ---------- BatchNorm apply + tanh ----------
__global__ void k_bnapply(const float* __restrict__ h, const float* __restrict__ stats,
                          const float* __restrict__ gamma, const float* __restrict__ beta,
                          float* __restrict__ out) {
    const float invN = 1.f / (float)NN;
    for (int idx = blockIdx.x * 256 + threadIdx.x; idx < NN * DIM;
         idx += gridDim.x * 256) {
        int o = idx & 127;
        float mean = stats[o] * invN;
        float var  = stats[128 + o] * invN - mean * mean;
        float v = (h[idx] - mean) * rsqrtf(var + BN_EPS) * gamma[o] + beta[o];
        out[idx] = tanhf(v);
    }
}

extern "C" void kernel_launch(void* const* d_in, const int* in_sizes, int n_in,
                              void* d_out, int out_size, void* d_ws, size_t ws_size,
                              hipStream_t stream) {
    const float* node_feat = (const float*)d_in[0];
    const float* edge_feat = (const float*)d_in[1];
    const float* W_R       = (const float*)d_in[2];
    const float* W_rel     = (const float*)d_in[3];
    const float* bn_gamma  = (const float*)d_in[4];
    const float* bn_beta   = (const float*)d_in[5];
    const float* enorm     = (const float*)d_in[6];
    const int*   src       = (const int*)d_in[7];
    const int*   dst       = (const int*)d_in[8];
    const int*   etype     = (const int*)d_in[9];

    float* ws_f = (float*)d_ws;
    int*   ws_i = (int*)d_ws;

    float*          h      = ws_f + WS_H;
    unsigned short* whi    = (unsigned short*)(ws_f + WS_WFRAG);
    unsigned short* wlo    = whi + NREL * 16384;
    float*          snorm  = ws_f + WS_SNORM;
    int*            ssrc   = ws_i + WS_SSRC;
    int*            sdst   = ws_i + WS_SDST;
    int*            cnt    = ws_i + WS_CNT;
    int*            off    = ws_i + WS_OFF;
    int*            cursor = ws_i + WS_CURSOR;
    float*          stats  = ws_f + WS_STATS;

    float* out_h  = (float*)d_out;              // N*128
    float* out2   = (float*)d_out + NN * DIM;   // 32*128

    hipMemsetAsync(ws_i + WS_CNT, 0, (WS_END - WS_CNT) * sizeof(int), stream);

    k_prep    <<<2144, 256, 0, stream>>>(edge_feat, W_R, W_rel, etype,
                                         whi, wlo, out2, cnt);
    k_scan    <<<1, 64, 0, stream>>>(cnt, off, cursor);
    k_scatter <<<(NE + 2047) / 2048, 256, 0, stream>>>(etype, src, dst, enorm,
                                                       cursor, ssrc, sdst, snorm, h);
    k_gemm    <<<NREL * 8, 512, 0, stream>>>(node_feat, whi, wlo, ssrc, sdst,
                                             snorm, off, h);
    k_bnstat  <<<512, 256, 0, stream>>>(h, stats);
    k_bnapply <<<2048, 256, 0, stream>>>(h, stats, bn_gamma, bn_beta, out_h);
}